// Round 1
// baseline (220.835 us; speedup 1.0000x reference)
//
#include <hip/hip_runtime.h>
#include <math.h>

#define NFFT  4096
#define MHALF 2048   // complex FFT size (N/2)
#define HOPSZ 1024
#define LX    441000
#define NB    32
#define NF    431
#define NK    2049
#define NWG   (NB * NF)   // 13792
#define CHUNK (NWG / 8)   // 1724, exact

// ws layout (floats): [0,4096) window*scale | [4096,6144) twiddle exp(-2pi i t/2048), t<1024
//                     | [6144,10242) exp(-2pi i k/4096), k<=2048
__global__ void stft_init(float* __restrict__ ws) {
  int i = blockIdx.x * blockDim.x + threadIdx.x;
  const double PI = 3.14159265358979323846;
  if (i < 4096) {
    double w = 0.5 * (1.0 - cos(2.0 * PI * (double)i / 4096.0)) * (1.0 / 64.0);
    ws[i] = (float)w;
  }
  if (i < 1024) {
    double a = -2.0 * PI * (double)i / 2048.0;
    ws[4096 + 2 * i]     = (float)cos(a);
    ws[4096 + 2 * i + 1] = (float)sin(a);
  }
  if (i < 2049) {
    double a = -2.0 * PI * (double)i / 4096.0;
    ws[6144 + 2 * i]     = (float)cos(a);
    ws[6144 + 2 * i + 1] = (float)sin(a);
  }
}

__global__ __launch_bounds__(256) void stft_fft(const float* __restrict__ x,
                                                const float* __restrict__ ws,
                                                float* __restrict__ out) {
  __shared__ float2 bufA[2048];
  __shared__ float2 bufB[2048];
  __shared__ float2 twm[1024];

  const int tid = threadIdx.x;
  // chunked XCD-bijective swizzle: consecutive frames stay on one XCD -> L2 write combining
  const int wid = (blockIdx.x & 7) * CHUNK + (blockIdx.x >> 3);
  const int b = wid / NF;
  const int f = wid - b * NF;

  const float*  win   = ws;
  const float2* winv  = (const float2*)ws;
  const float2* twm_g = (const float2*)(ws + 4096);
  const float2* tw4   = (const float2*)(ws + 6144);

  for (int i = tid; i < 1024; i += 256) twm[i] = twm_g[i];

  const float* xb = x + (size_t)b * LX;
  const int base = f * HOPSZ - MHALF;
  // load frame, apply window, pack z[m] = y[2m] + i*y[2m+1]
  if (base >= 0 && base + NFFT <= LX) {
    const float2* xv = (const float2*)(xb + base);  // base even -> aligned
    for (int i = tid; i < 2048; i += 256) {
      float2 v = xv[i];
      float2 w = winv[i];
      bufA[i] = make_float2(v.x * w.x, v.y * w.y);
    }
  } else {
    for (int i = tid; i < 2048; i += 256) {
      int s0 = base + 2 * i;
      int s1 = s0 + 1;
      s0 = (s0 < 0) ? -s0 : ((s0 >= LX) ? (2 * LX - 2 - s0) : s0);
      s1 = (s1 < 0) ? -s1 : ((s1 >= LX) ? (2 * LX - 2 - s1) : s1);
      bufA[i] = make_float2(xb[s0] * win[2 * i], xb[s1] * win[2 * i + 1]);
    }
  }
  __syncthreads();

  // Stockham radix-2 DIF, 11 stages, natural-order output, forward sign e^{-i}
  float2* Xp = bufA;
  float2* Yp = bufB;
  int s = 1;
  for (int st = 0; st < 11; ++st) {
#pragma unroll
    for (int r = 0; r < 4; ++r) {
      const int j = tid + (r << 8);
      const int q = j & (s - 1);
      const float2 a  = Xp[j];
      const float2 bb = Xp[j + 1024];
      const float2 w  = twm[j & ~(s - 1)];
      const float dx = a.x - bb.x, dy = a.y - bb.y;
      const int o0 = 2 * j - q;
      Yp[o0]     = make_float2(a.x + bb.x, a.y + bb.y);
      Yp[o0 + s] = make_float2(dx * w.x - dy * w.y, dx * w.y + dy * w.x);
    }
    __syncthreads();
    float2* t = Xp; Xp = Yp; Yp = t;
    s <<= 1;
  }

  // real-FFT recombination: X[k] = Xe + W*Xo ; X[2048-k] = conj(Xe - W*Xo)
  float2* __restrict__ op = (float2*)out;
  const size_t obase = ((size_t)b * NK) * NF + f;  // float2 index of (b, k=0, f)
  for (int k = tid; k <= 1024; k += 256) {
    if (k == 0) {
      float2 z = Xp[0];
      op[obase]                      = make_float2(z.x + z.y, 0.0f);
      op[obase + (size_t)2048 * NF]  = make_float2(z.x - z.y, 0.0f);
    } else if (k == 1024) {
      float2 z = Xp[1024];
      op[obase + (size_t)1024 * NF]  = make_float2(z.x, -z.y);
    } else {
      float2 zk = Xp[k];
      float2 zm = Xp[2048 - k];
      float xex = 0.5f * (zk.x + zm.x);
      float xey = 0.5f * (zk.y - zm.y);
      float ddx = zk.x - zm.x;
      float ddy = zk.y + zm.y;
      float xox = 0.5f * ddy;
      float xoy = -0.5f * ddx;
      float2 w = tw4[k];
      float tx = w.x * xox - w.y * xoy;
      float ty = w.x * xoy + w.y * xox;
      op[obase + (size_t)k * NF]          = make_float2(xex + tx, xey + ty);
      op[obase + (size_t)(2048 - k) * NF] = make_float2(xex - tx, -(xey - ty));
    }
  }
}

extern "C" void kernel_launch(void* const* d_in, const int* in_sizes, int n_in,
                              void* d_out, int out_size, void* d_ws, size_t ws_size,
                              hipStream_t stream) {
  const float* x = (const float*)d_in[0];
  float* ws = (float*)d_ws;     // needs 10242 floats (~41 KB)
  float* out = (float*)d_out;
  stft_init<<<16, 256, 0, stream>>>(ws);
  stft_fft<<<NWG, 256, 0, stream>>>(x, ws, out);
}

// Round 2
// 192.992 us; speedup vs baseline: 1.1443x; 1.1443x over previous
//
#include <hip/hip_runtime.h>
#include <math.h>

#define NFFT  4096
#define MHALF 2048   // complex FFT size (N/2)
#define HOPSZ 1024
#define LX    441000
#define NB    32
#define NF    431
#define NK    2049
#define NWG   (NB * NF)   // 13792
#define CHUNK (NWG / 8)   // 1724, exact

// LDS index swizzle: XOR bits 7..4 into 3..0. Bijective on [0,2048).
// Puts every stage's b64 read AND write pattern at the bank floor.
#define SW(A) ((A) ^ (((A) >> 4) & 0xF))

__device__ __forceinline__ float2 cadd(float2 a, float2 b){ return make_float2(a.x+b.x, a.y+b.y); }
__device__ __forceinline__ float2 csub(float2 a, float2 b){ return make_float2(a.x-b.x, a.y-b.y); }
__device__ __forceinline__ float2 cmul(float2 a, float2 b){
  return make_float2(fmaf(a.x, b.x, -(a.y*b.y)), fmaf(a.x, b.y, a.y*b.x));
}

// ws layout (floats): [0,4096) window*scale | [4096,6144) exp(-2pi i t/2048), t<1024
//                     | [6144,10242) exp(-2pi i k/4096), k<=2048
__global__ void stft_init(float* __restrict__ ws) {
  int i = blockIdx.x * blockDim.x + threadIdx.x;
  const double PI = 3.14159265358979323846;
  if (i < 4096) {
    double w = 0.5 * (1.0 - cos(2.0 * PI * (double)i / 4096.0)) * (1.0 / 64.0);
    ws[i] = (float)w;
  }
  if (i < 1024) {
    double a = -2.0 * PI * (double)i / 2048.0;
    ws[4096 + 2 * i]     = (float)cos(a);
    ws[4096 + 2 * i + 1] = (float)sin(a);
  }
  if (i < 2049) {
    double a = -2.0 * PI * (double)i / 4096.0;
    ws[6144 + 2 * i]     = (float)cos(a);
    ws[6144 + 2 * i + 1] = (float)sin(a);
  }
}

// One Stockham DIF radix-8 stage, span S. j in [0,256). N=2048 complex.
// Y[q + 8t + u*S] = W_N^{u*t} * DFT8(a)_u,  q = j mod S, t = j - q.
template<int S>
__device__ __forceinline__ void radix8_stage(const float2* __restrict__ X,
                                             float2* __restrict__ Y,
                                             const float2* __restrict__ twg,
                                             int j) {
  const int q = j & (S - 1);
  const int t = j - q;
  float2 a0 = X[SW(j)];
  float2 a1 = X[SW(j + 256)];
  float2 a2 = X[SW(j + 512)];
  float2 a3 = X[SW(j + 768)];
  float2 a4 = X[SW(j + 1024)];
  float2 a5 = X[SW(j + 1280)];
  float2 a6 = X[SW(j + 1536)];
  float2 a7 = X[SW(j + 1792)];

  float2 t0 = cadd(a0, a4), t1 = csub(a0, a4);
  float2 t2 = cadd(a2, a6), t3 = csub(a2, a6);
  float2 t4 = cadd(a1, a5), t5 = csub(a1, a5);
  float2 t6 = cadd(a3, a7), t7 = csub(a3, a7);

  const float K = 0.70710678118654752f;
  // W8 = (1-i)/sqrt2, W8^3 = (-1-i)/sqrt2
  float2 wt5  = make_float2(K * (t5.x + t5.y), K * (t5.y - t5.x));   // W8   * t5
  float2 w3t7 = make_float2(K * (t7.y - t7.x), -K * (t7.x + t7.y));  // W8^3 * t7
  float2 wt7  = make_float2(K * (t7.x + t7.y), K * (t7.y - t7.x));   // W8   * t7
  float2 w3t5 = make_float2(K * (t5.y - t5.x), -K * (t5.x + t5.y));  // W8^3 * t5

  float2 e0 = cadd(t0, t2), e1 = csub(t0, t2);
  float2 f0 = cadd(t4, t6), f1 = csub(t4, t6);
  float2 B0 = cadd(e0, f0);
  float2 B4 = csub(e0, f0);
  float2 B2 = make_float2(e1.x + f1.y, e1.y - f1.x);  // e1 - i*f1
  float2 B6 = make_float2(e1.x - f1.y, e1.y + f1.x);  // e1 + i*f1
  float2 g0 = make_float2(t1.x + t3.y, t1.y - t3.x);  // t1 - i*t3
  float2 g1 = make_float2(t1.x - t3.y, t1.y + t3.x);  // t1 + i*t3
  float2 h0 = cadd(wt5, w3t7);
  float2 h1 = cadd(wt7, w3t5);
  float2 B1 = cadd(g0, h0);
  float2 B5 = csub(g0, h0);
  float2 B3 = cadd(g1, h1);
  float2 B7 = csub(g1, h1);

  float2 w1 = twg[t];          // exp(-2pi i t/2048), t < 256 -> L1-hot
  float2 w2 = cmul(w1, w1);
  float2 w3 = cmul(w2, w1);
  float2 w4 = cmul(w2, w2);
  float2 w5 = cmul(w3, w2);
  float2 w6 = cmul(w3, w3);
  float2 w7 = cmul(w4, w3);

  const int o = q + 8 * t;     // == 8j - 7q
  Y[SW(o)]         = B0;
  Y[SW(o + S)]     = cmul(w1, B1);
  Y[SW(o + 2 * S)] = cmul(w2, B2);
  Y[SW(o + 3 * S)] = cmul(w3, B3);
  Y[SW(o + 4 * S)] = cmul(w4, B4);
  Y[SW(o + 5 * S)] = cmul(w5, B5);
  Y[SW(o + 6 * S)] = cmul(w6, B6);
  Y[SW(o + 7 * S)] = cmul(w7, B7);
}

// Final radix-4 stage, S=512: j in [0,512), q=j, t=0 (no twiddles).
__device__ __forceinline__ void radix4_stage512(const float2* __restrict__ X,
                                                float2* __restrict__ Y, int j) {
  float2 a0 = X[SW(j)];
  float2 a1 = X[SW(j + 512)];
  float2 a2 = X[SW(j + 1024)];
  float2 a3 = X[SW(j + 1536)];
  float2 e0 = cadd(a0, a2), e1 = csub(a0, a2);
  float2 o0 = cadd(a1, a3), o1 = csub(a1, a3);
  Y[SW(j)]        = cadd(e0, o0);
  Y[SW(j + 512)]  = make_float2(e1.x + o1.y, e1.y - o1.x);  // e1 - i*o1
  Y[SW(j + 1024)] = csub(e0, o0);
  Y[SW(j + 1536)] = make_float2(e1.x - o1.y, e1.y + o1.x);  // e1 + i*o1
}

__global__ __launch_bounds__(256) void stft_fft(const float* __restrict__ x,
                                                const float* __restrict__ ws,
                                                float* __restrict__ out) {
  __shared__ float2 bufA[2048];
  __shared__ float2 bufB[2048];

  const int tid = threadIdx.x;
  const int wid = (blockIdx.x & 7) * CHUNK + (blockIdx.x >> 3);
  const int b = wid / NF;
  const int f = wid - b * NF;

  const float*  win  = ws;
  const float2* winv = (const float2*)ws;
  const float2* twg  = (const float2*)(ws + 4096);
  const float2* tw4  = (const float2*)(ws + 6144);

  const float* xb = x + (size_t)b * LX;
  const int base = f * HOPSZ - MHALF;
  if (base >= 0 && base + NFFT <= LX) {
    const float2* xv = (const float2*)(xb + base);  // base even -> aligned
    for (int i = tid; i < 2048; i += 256) {
      float2 v = xv[i];
      float2 w = winv[i];
      bufA[SW(i)] = make_float2(v.x * w.x, v.y * w.y);
    }
  } else {
    for (int i = tid; i < 2048; i += 256) {
      int s0 = base + 2 * i;
      int s1 = s0 + 1;
      s0 = (s0 < 0) ? -s0 : ((s0 >= LX) ? (2 * LX - 2 - s0) : s0);
      s1 = (s1 < 0) ? -s1 : ((s1 >= LX) ? (2 * LX - 2 - s1) : s1);
      bufA[SW(i)] = make_float2(xb[s0] * win[2 * i], xb[s1] * win[2 * i + 1]);
    }
  }
  __syncthreads();

  radix8_stage<1>(bufA, bufB, twg, tid);
  __syncthreads();
  radix8_stage<8>(bufB, bufA, twg, tid);
  __syncthreads();
  radix8_stage<64>(bufA, bufB, twg, tid);
  __syncthreads();
  radix4_stage512(bufB, bufA, tid);
  radix4_stage512(bufB, bufA, tid + 256);
  __syncthreads();

  // real-FFT recombination: X[k] = Xe + W*Xo ; X[2048-k] = conj(Xe - W*Xo)
  float2* __restrict__ op = (float2*)out;
  const size_t obase = ((size_t)b * NK) * NF + f;
  for (int k = tid; k <= 1024; k += 256) {
    if (k == 0) {
      float2 z = bufA[SW(0)];
      op[obase]                     = make_float2(z.x + z.y, 0.0f);
      op[obase + (size_t)2048 * NF] = make_float2(z.x - z.y, 0.0f);
    } else if (k == 1024) {
      float2 z = bufA[SW(1024)];
      op[obase + (size_t)1024 * NF] = make_float2(z.x, -z.y);
    } else {
      float2 zk = bufA[SW(k)];
      float2 zm = bufA[SW(2048 - k)];
      float xex = 0.5f * (zk.x + zm.x);
      float xey = 0.5f * (zk.y - zm.y);
      float ddx = zk.x - zm.x;
      float ddy = zk.y + zm.y;
      float xox = 0.5f * ddy;
      float xoy = -0.5f * ddx;
      float2 w = tw4[k];
      float tx = w.x * xox - w.y * xoy;
      float ty = w.x * xoy + w.y * xox;
      op[obase + (size_t)k * NF]          = make_float2(xex + tx, xey + ty);
      op[obase + (size_t)(2048 - k) * NF] = make_float2(xex - tx, -(xey - ty));
    }
  }
}

extern "C" void kernel_launch(void* const* d_in, const int* in_sizes, int n_in,
                              void* d_out, int out_size, void* d_ws, size_t ws_size,
                              hipStream_t stream) {
  const float* x = (const float*)d_in[0];
  float* ws = (float*)d_ws;     // needs 10242 floats (~41 KB)
  float* out = (float*)d_out;
  stft_init<<<16, 256, 0, stream>>>(ws);
  stft_fft<<<NWG, 256, 0, stream>>>(x, ws, out);
}

// Round 3
// 188.337 us; speedup vs baseline: 1.1726x; 1.0247x over previous
//
#include <hip/hip_runtime.h>
#include <hip/hip_fp16.h>
#include <math.h>

#define NFFT  4096
#define MHALF 2048   // complex FFT size (N/2)
#define HOPSZ 1024
#define LX    441000
#define NB    32
#define NF    431
#define NK    2049
#define G     4
#define NFB   108               // ceil(431/4)
#define NWG2  (NB * NFB)        // 3456
#define CHUNK2 (NWG2 / 8)       // 432, exact

// FFT-buffer swizzle: XOR bits 7..4 into 3..0. Bank-conflict floor for all stages.
#define SW(A) ((A) ^ (((A) >> 4) & 0xF))
// Staging layout: half2 slot for (complex idx, frame g). XOR spreads the
// stride-4 patterns across banks. Bijective: g -> g^c per idx.
#define ZL(idx, g) (((idx) << 2) + ((g) ^ (((idx) >> 2) & 3)))

__device__ __forceinline__ float2 cadd(float2 a, float2 b){ return make_float2(a.x+b.x, a.y+b.y); }
__device__ __forceinline__ float2 csub(float2 a, float2 b){ return make_float2(a.x-b.x, a.y-b.y); }
__device__ __forceinline__ float2 cmul(float2 a, float2 b){
  return make_float2(fmaf(a.x, b.x, -(a.y*b.y)), fmaf(a.x, b.y, a.y*b.x));
}

// ws layout (floats): [0,4096) window*scale | [4096,6144) exp(-2pi i t/2048), t<1024
//                     | [6144,10242) exp(-2pi i k/4096), k<=2048
__global__ void stft_init(float* __restrict__ ws) {
  int i = blockIdx.x * blockDim.x + threadIdx.x;
  const double PI = 3.14159265358979323846;
  if (i < 4096) {
    double w = 0.5 * (1.0 - cos(2.0 * PI * (double)i / 4096.0)) * (1.0 / 64.0);
    ws[i] = (float)w;
  }
  if (i < 1024) {
    double a = -2.0 * PI * (double)i / 2048.0;
    ws[4096 + 2 * i]     = (float)cos(a);
    ws[4096 + 2 * i + 1] = (float)sin(a);
  }
  if (i < 2049) {
    double a = -2.0 * PI * (double)i / 4096.0;
    ws[6144 + 2 * i]     = (float)cos(a);
    ws[6144 + 2 * i + 1] = (float)sin(a);
  }
}

// In-place Stockham DIF radix-8 stage, span S, N=2048 complex, 256 threads.
// Read-all -> barrier -> write-all (whole array is in registers across the block).
template<int S>
__device__ __forceinline__ void radix8_inplace(float2* __restrict__ X,
                                               const float2* __restrict__ twg,
                                               int j) {
  const int q = j & (S - 1);
  const int t = j - q;
  float2 a0 = X[SW(j)];
  float2 a1 = X[SW(j + 256)];
  float2 a2 = X[SW(j + 512)];
  float2 a3 = X[SW(j + 768)];
  float2 a4 = X[SW(j + 1024)];
  float2 a5 = X[SW(j + 1280)];
  float2 a6 = X[SW(j + 1536)];
  float2 a7 = X[SW(j + 1792)];
  __syncthreads();

  float2 t0 = cadd(a0, a4), t1 = csub(a0, a4);
  float2 t2 = cadd(a2, a6), t3 = csub(a2, a6);
  float2 t4 = cadd(a1, a5), t5 = csub(a1, a5);
  float2 t6 = cadd(a3, a7), t7 = csub(a3, a7);

  const float K = 0.70710678118654752f;
  float2 wt5  = make_float2(K * (t5.x + t5.y), K * (t5.y - t5.x));   // W8   * t5
  float2 w3t7 = make_float2(K * (t7.y - t7.x), -K * (t7.x + t7.y));  // W8^3 * t7
  float2 wt7  = make_float2(K * (t7.x + t7.y), K * (t7.y - t7.x));   // W8   * t7
  float2 w3t5 = make_float2(K * (t5.y - t5.x), -K * (t5.x + t5.y));  // W8^3 * t5

  float2 e0 = cadd(t0, t2), e1 = csub(t0, t2);
  float2 f0 = cadd(t4, t6), f1 = csub(t4, t6);
  float2 B0 = cadd(e0, f0);
  float2 B4 = csub(e0, f0);
  float2 B2 = make_float2(e1.x + f1.y, e1.y - f1.x);
  float2 B6 = make_float2(e1.x - f1.y, e1.y + f1.x);
  float2 g0 = make_float2(t1.x + t3.y, t1.y - t3.x);
  float2 g1 = make_float2(t1.x - t3.y, t1.y + t3.x);
  float2 h0 = cadd(wt5, w3t7);
  float2 h1 = cadd(wt7, w3t5);
  float2 B1 = cadd(g0, h0);
  float2 B5 = csub(g0, h0);
  float2 B3 = cadd(g1, h1);
  float2 B7 = csub(g1, h1);

  float2 w1 = twg[t];
  float2 w2 = cmul(w1, w1);
  float2 w3 = cmul(w2, w1);
  float2 w4 = cmul(w2, w2);
  float2 w5 = cmul(w3, w2);
  float2 w6 = cmul(w3, w3);
  float2 w7 = cmul(w4, w3);

  const int o = q + 8 * t;
  X[SW(o)]         = B0;
  X[SW(o + S)]     = cmul(w1, B1);
  X[SW(o + 2 * S)] = cmul(w2, B2);
  X[SW(o + 3 * S)] = cmul(w3, B3);
  X[SW(o + 4 * S)] = cmul(w4, B4);
  X[SW(o + 5 * S)] = cmul(w5, B5);
  X[SW(o + 6 * S)] = cmul(w6, B6);
  X[SW(o + 7 * S)] = cmul(w7, B7);
}

__device__ __forceinline__ void zput(__half2* __restrict__ zst, int idx, int g, float2 v) {
  zst[ZL(idx, g)] = __floats2half2_rn(v.x, v.y);
}

// Final radix-4 stage (S=512, twiddle-free): read fbuf, write half2 staging.
__device__ __forceinline__ void radix4_final_store(const float2* __restrict__ X,
                                                   __half2* __restrict__ zst,
                                                   int t, int g) {
  float2 v0 = X[SW(t)];
  float2 v1 = X[SW(t + 256)];
  float2 v2 = X[SW(t + 512)];
  float2 v3 = X[SW(t + 768)];
  float2 v4 = X[SW(t + 1024)];
  float2 v5 = X[SW(t + 1280)];
  float2 v6 = X[SW(t + 1536)];
  float2 v7 = X[SW(t + 1792)];
  {  // butterfly j = t: inputs X[t], X[t+512], X[t+1024], X[t+1536]
    float2 e0 = cadd(v0, v4), e1 = csub(v0, v4);
    float2 o0 = cadd(v2, v6), o1 = csub(v2, v6);
    zput(zst, t,        g, cadd(e0, o0));
    zput(zst, t + 512,  g, make_float2(e1.x + o1.y, e1.y - o1.x));
    zput(zst, t + 1024, g, csub(e0, o0));
    zput(zst, t + 1536, g, make_float2(e1.x - o1.y, e1.y + o1.x));
  }
  {  // butterfly j = t+256
    float2 e0 = cadd(v1, v5), e1 = csub(v1, v5);
    float2 o0 = cadd(v3, v7), o1 = csub(v3, v7);
    zput(zst, t + 256,  g, cadd(e0, o0));
    zput(zst, t + 768,  g, make_float2(e1.x + o1.y, e1.y - o1.x));
    zput(zst, t + 1280, g, csub(e0, o0));
    zput(zst, t + 1792, g, make_float2(e1.x - o1.y, e1.y + o1.x));
  }
}

__global__ __launch_bounds__(256) void stft_fft(const float* __restrict__ x,
                                                const float* __restrict__ ws,
                                                float* __restrict__ out) {
  __shared__ float2  fbuf[2048];       // 16 KB, SW-swizzled FFT workspace
  __shared__ __half2 zst[2048 * G];    // 32 KB, staged spectra of G frames

  const int tid = threadIdx.x;
  const int wid = (blockIdx.x & 7) * CHUNK2 + (blockIdx.x >> 3);
  const int b  = wid / NFB;
  const int fb = wid - b * NFB;
  const int f0 = fb * G;
  const int gcnt = (NF - f0 < G) ? (NF - f0) : G;

  const float*  win  = ws;
  const float2* winv = (const float2*)ws;
  const float2* twg  = (const float2*)(ws + 4096);
  const float2* tw4  = (const float2*)(ws + 6144);
  const float* xb = x + (size_t)b * LX;

  for (int g = 0; g < gcnt; ++g) {
    const int f = f0 + g;
    const int base = f * HOPSZ - MHALF;
    if (base >= 0 && base + NFFT <= LX) {
      const float2* xv = (const float2*)(xb + base);  // base even -> aligned
      for (int i = tid; i < 2048; i += 256) {
        float2 v = xv[i];
        float2 w = winv[i];
        fbuf[SW(i)] = make_float2(v.x * w.x, v.y * w.y);
      }
    } else {
      for (int i = tid; i < 2048; i += 256) {
        int s0 = base + 2 * i;
        int s1 = s0 + 1;
        s0 = (s0 < 0) ? -s0 : ((s0 >= LX) ? (2 * LX - 2 - s0) : s0);
        s1 = (s1 < 0) ? -s1 : ((s1 >= LX) ? (2 * LX - 2 - s1) : s1);
        fbuf[SW(i)] = make_float2(xb[s0] * win[2 * i], xb[s1] * win[2 * i + 1]);
      }
    }
    __syncthreads();

    radix8_inplace<1>(fbuf, twg, tid);
    __syncthreads();
    radix8_inplace<8>(fbuf, twg, tid);
    __syncthreads();
    radix8_inplace<64>(fbuf, twg, tid);
    __syncthreads();
    radix4_final_store(fbuf, zst, tid, g);
    __syncthreads();   // protects fbuf reuse next iter AND publishes zst
  }

  // Write phase: lane -> (k block, g). Consecutive lanes cover consecutive
  // frames then k -> 32B-contiguous chunks per k, ~4x fewer store lines.
  {
    const int g  = tid & 3;
    const int kk = tid >> 2;          // 0..63
    const int f  = f0 + g;
    const bool act = (g < gcnt);
    float2* __restrict__ op = (float2*)out;
    const size_t ob = (size_t)b * NK * NF + f;
    float2 z0save = make_float2(0.f, 0.f);
    for (int it = 0; it < 32; ++it) {
      const int k  = kk + (it << 6);            // 0..2047
      const int km = (2048 - k) & 2047;
      float2 zk = __half22float2(zst[ZL(k,  g)]);
      float2 zm = __half22float2(zst[ZL(km, g)]);
      if (it == 0) z0save = zk;
      // uniform real-FFT recombination, valid for all k in [0,2048)
      float xex = 0.5f * (zk.x + zm.x);
      float xey = 0.5f * (zk.y - zm.y);
      float xox = 0.5f * (zk.y + zm.y);
      float xoy = 0.5f * (zm.x - zk.x);
      float2 w = tw4[k];
      float tx = w.x * xox - w.y * xoy;
      float ty = w.x * xoy + w.y * xox;
      if (act) op[ob + (size_t)k * NF] = make_float2(xex + tx, xey + ty);
    }
    if (act && kk == 0) {  // k = 2048 row (Nyquist of the 4096-pt rfft)
      op[ob + (size_t)2048 * NF] = make_float2(z0save.x - z0save.y, 0.0f);
    }
  }
}

extern "C" void kernel_launch(void* const* d_in, const int* in_sizes, int n_in,
                              void* d_out, int out_size, void* d_ws, size_t ws_size,
                              hipStream_t stream) {
  const float* x = (const float*)d_in[0];
  float* ws = (float*)d_ws;     // needs 10242 floats (~41 KB)
  float* out = (float*)d_out;
  stft_init<<<16, 256, 0, stream>>>(ws);
  stft_fft<<<NWG2, 256, 0, stream>>>(x, ws, out);
}